// Round 3
// baseline (5762.621 us; speedup 1.0000x reference)
//
#include <hip/hip_runtime.h>
#include <hip/hip_cooperative_groups.h>
#include <stdint.h>

#define N 2560
#define NSUP 640
#define NQ 1920
#define NCLS 128
#define DF 8192
#define CAP 1024
#define TITER 64
#define RPB 5
#define GBLK 512
#define EPSF 2.220446049250313e-16f

typedef __attribute__((ext_vector_type(8))) short bf16x8;
typedef __attribute__((ext_vector_type(4))) float f32x4;

// ---------- helpers ----------
__device__ __forceinline__ unsigned short f2bf(float f) {
  unsigned u = __float_as_uint(f);
  return (unsigned short)((u + 0x7FFFu + ((u >> 16) & 1u)) >> 16);  // RNE
}
__device__ __forceinline__ unsigned sortkey(float f) {
  unsigned u = __float_as_uint(f);
  return (u & 0x80000000u) ? ~u : (u | 0x80000000u);
}
__device__ __forceinline__ void load_lds16(const void* g, void* l) {
  __builtin_amdgcn_global_load_lds((const __attribute__((address_space(1))) void*)g,
                                   (__attribute__((address_space(3))) void*)l, 16, 0, 0);
}

// ---------- 1. fp32 -> bf16 copy + row sumsq + rho table ----------
__global__ void k_prep(const float* __restrict__ feats, unsigned short* __restrict__ fb,
                       float* __restrict__ sq, const float* __restrict__ alpha,
                       float* __restrict__ rho_tab) {
  int i = blockIdx.x, t = threadIdx.x;
  const float4* src = (const float4*)(feats + (size_t)i * DF);
  ushort4* dst = (ushort4*)(fb + (size_t)i * DF);
  float s = 0.f;
#pragma unroll
  for (int it = 0; it < 8; ++it) {
    float4 v = src[it * 256 + t];
    s = fmaf(v.x, v.x, s); s = fmaf(v.y, v.y, s);
    s = fmaf(v.z, v.z, s); s = fmaf(v.w, v.w, s);
    ushort4 o; o.x = f2bf(v.x); o.y = f2bf(v.y); o.z = f2bf(v.z); o.w = f2bf(v.w);
    dst[it * 256 + t] = o;
  }
  __shared__ float red[256];
  red[t] = s; __syncthreads();
  for (int o = 128; o > 0; o >>= 1) { if (t < o) red[t] += red[t + o]; __syncthreads(); }
  if (t == 0) sq[i] = red[0];
  if (i == 0 && t == 0) {  // Chebyshev rho recurrence (theta=1, delta=alpha)
    float a = alpha[0];
    float rho = a; rho_tab[0] = rho;
    for (int k2 = 1; k2 < 128; ++k2) { rho = 1.f / (2.f / a - rho); rho_tab[k2] = rho; }
  }
}

// ---------- 2. C = fb @ fb^T, symmetric-half: 210 lower-tri 128x128 tiles ----------
__global__ __launch_bounds__(256, 2) void k_gemm(const unsigned short* __restrict__ fb,
                                                 float* __restrict__ C) {
  __shared__ __align__(16) unsigned short As[128 * 32];
  __shared__ __align__(16) unsigned short Bs[128 * 32];
  int bid = blockIdx.x;
  int bx = (int)((sqrtf(8.0f * (float)bid + 1.0f) - 1.0f) * 0.5f);
  while ((bx + 1) * (bx + 2) / 2 <= bid) ++bx;
  while (bx * (bx + 1) / 2 > bid) --bx;
  int by = bid - bx * (bx + 1) / 2;            // by <= bx
  const int rA = by * 128, rB = bx * 128;
  const int t = threadIdx.x, w = t >> 6, l = t & 63;
  const int q = l >> 4, m = l & 15;
  const int wr = w >> 1, wc = w & 1;
  f32x4 acc[4][4];
#pragma unroll
  for (int a2 = 0; a2 < 4; ++a2)
#pragma unroll
    for (int b2 = 0; b2 < 4; ++b2) acc[a2][b2] = (f32x4){0.f, 0.f, 0.f, 0.f};

  const int c0 = (w * 2 + 0) * 64 + l;   // chunk ids (16B chunks of the 8KB tile)
  const int c1 = (w * 2 + 1) * 64 + l;
  const int r0 = c0 >> 2, o0 = (c0 & 3) * 8;
  const int r1 = c1 >> 2, o1 = (c1 & 3) * 8;
  char* lA0 = (char*)As + (w * 2 + 0) * 1024;
  char* lA1 = (char*)As + (w * 2 + 1) * 1024;
  char* lB0 = (char*)Bs + (w * 2 + 0) * 1024;
  char* lB1 = (char*)Bs + (w * 2 + 1) * 1024;

  for (int k0 = 0; k0 < DF; k0 += 32) {
    load_lds16(fb + (size_t)(rA + r0) * DF + k0 + o0, lA0);
    load_lds16(fb + (size_t)(rA + r1) * DF + k0 + o1, lA1);
    load_lds16(fb + (size_t)(rB + r0) * DF + k0 + o0, lB0);
    load_lds16(fb + (size_t)(rB + r1) * DF + k0 + o1, lB1);
    asm volatile("s_waitcnt vmcnt(0)" ::: "memory");
    __syncthreads();
    bf16x8 af[4], bv[4];
#pragma unroll
    for (int im = 0; im < 4; ++im)
      af[im] = *(const bf16x8*)(As + (wr * 64 + im * 16 + m) * 32 + q * 8);
#pragma unroll
    for (int in = 0; in < 4; ++in)
      bv[in] = *(const bf16x8*)(Bs + (wc * 64 + in * 16 + m) * 32 + q * 8);
#pragma unroll
    for (int im = 0; im < 4; ++im)
#pragma unroll
      for (int in = 0; in < 4; ++in)
        acc[im][in] = __builtin_amdgcn_mfma_f32_16x16x32_bf16(af[im], bv[in], acc[im][in], 0, 0, 0);
    __syncthreads();
  }
#pragma unroll
  for (int im = 0; im < 4; ++im) {
    int row0 = rA + wr * 64 + im * 16 + q * 4;
#pragma unroll
    for (int in = 0; in < 4; ++in) {
      int col = rB + wc * 64 + in * 16 + m;
#pragma unroll
      for (int rg = 0; rg < 4; ++rg) {
        C[(size_t)(row0 + rg) * N + col] = acc[im][in][rg];
        C[(size_t)col * N + row0 + rg] = acc[im][in][rg];   // symmetric image
      }
    }
  }
}

// ---------- 3. per-row top-20 (key = 2*C - sq_j, ties -> lower idx), set bits ----------
__global__ void k_topk(const float* __restrict__ C, const float* __restrict__ sq,
                       unsigned* __restrict__ M) {
  int i = blockIdx.x * 4 + (threadIdx.x >> 6);
  int lane = threadIdx.x & 63;
  const float* Crow = C + (size_t)i * N;
  unsigned kk[40];
#pragma unroll
  for (int s = 0; s < 40; ++s) {
    int j = lane + (s << 6);
    kk[s] = sortkey(2.f * Crow[j] - sq[j]);
  }
  unsigned long long removed = 0ull;
  unsigned myj = 0u;
  for (int t = 0; t < 20; ++t) {
    unsigned bk = 0u; int bs = -1;
#pragma unroll
    for (int s = 0; s < 40; ++s)
      if (!((removed >> s) & 1ull) && kk[s] > bk) { bk = kk[s]; bs = s; }
    unsigned long long packed = (bs < 0) ? 0ull
        : ((((unsigned long long)bk) << 32) |
           (unsigned long long)(0xFFFFFFFFu - (unsigned)(lane + (bs << 6))));
#pragma unroll
    for (int off2 = 32; off2 > 0; off2 >>= 1) {
      unsigned long long o = __shfl_xor(packed, off2, 64);
      if (o > packed) packed = o;
    }
    unsigned jw = 0xFFFFFFFFu - (unsigned)(packed & 0xFFFFFFFFull);
    if ((int)(jw & 63u) == lane) removed |= 1ull << (jw >> 6);
    if (t == lane) myj = jw;
  }
  if (lane < 20) atomicOr(&M[(size_t)i * 80 + (myj >> 5)], 1u << (myj & 31u));
}

// ---------- 4. symmetrize mask, build padded CSR of W, row sums D, dsi ----------
__global__ void k_csr(const float* __restrict__ C, const float* __restrict__ sq,
                      const unsigned* __restrict__ M, int* __restrict__ colG,
                      float* __restrict__ svalG, int* __restrict__ degG,
                      float* __restrict__ dsi) {
  int i = blockIdx.x, t = threadIdx.x;
  __shared__ unsigned Mrow[80];
  __shared__ int degs;
  __shared__ int cols[CAP];
  __shared__ float wvs[CAP];
  __shared__ float red[256];
  if (t < 80) Mrow[t] = M[(size_t)i * 80 + t];
  if (t == 0) degs = 0;
  __syncthreads();
  const float* Crow = C + (size_t)i * N;
  float sqi = sq[i];
  int iw = i >> 5; unsigned ib = 1u << (i & 31);
  float dsum = 0.f;
#pragma unroll
  for (int s = 0; s < 10; ++s) {
    int j = t + (s << 8);
    unsigned mij = (Mrow[j >> 5] >> (j & 31)) & 1u;
    unsigned mji = M[(size_t)j * 80 + iw] & ib;
    if (mij | (mji != 0u)) {
      float wv = expf((2.f * Crow[j] - sqi - sq[j]) * (1.f / 16384.f));
      int sl = atomicAdd(&degs, 1);
      if (sl < CAP) { cols[sl] = j; wvs[sl] = wv; }
      dsum += wv;
    }
  }
  red[t] = dsum; __syncthreads();
  for (int o = 128; o > 0; o >>= 1) { if (t < o) red[t] += red[t + o]; __syncthreads(); }
  if (t == 0) {
    degG[i] = degs > CAP ? CAP : degs;
    dsi[i] = 1.f / sqrtf(red[0] + EPSF);
  }
  __syncthreads();
  int dgc = degs > CAP ? CAP : degs;
  for (int sl = t; sl < dgc; sl += 256) {
    colG[(size_t)i * CAP + sl] = cols[sl];
    svalG[(size_t)i * CAP + sl] = wvs[sl];
  }
}

// ---------- 5. S edge values: w *= dsi_i * dsi_j ----------
__global__ void k_scale(const int* __restrict__ colG, float* __restrict__ svalG,
                        const int* __restrict__ degG, const float* __restrict__ dsi) {
  int i = blockIdx.x * 4 + (threadIdx.x >> 6);
  int lane = threadIdx.x & 63;
  float di = dsi[i];
  int dg = degG[i];
  for (int s = lane; s < dg; s += 64)
    svalG[(size_t)i * CAP + s] *= di * dsi[colG[(size_t)i * CAP + s]];
}

// ---------- 6. fused persistent Chebyshev solve + loss (cooperative) ----------
// 512 blocks x 512 threads; block b owns rows i = b + 512*k, k=0..4 (strided
// to spread hub rows). CSR staged to LDS once (42KB). c = t&127 (class),
// p = t>>7 (4 edge partitions, 4-deep unroll -> 16 gathers in flight/row).
__global__ __launch_bounds__(512, 4) void k_fused(
    const int* __restrict__ colG, const float* __restrict__ svalG,
    const int* __restrict__ degG, const float* __restrict__ rho_tab,
    const float* __restrict__ alpha, float* __restrict__ x,
    float* __restrict__ r, float* __restrict__ d0, float* __restrict__ d1,
    const int* __restrict__ slab, const int* __restrict__ qlab,
    float* lossSum, int* accCnt, float* out) {
  namespace cg = cooperative_groups;
  cg::grid_group grid = cg::this_grid();
  __shared__ int lcol[RPB * CAP];
  __shared__ float lval[RPB * CAP];
  __shared__ float partial[512];
  __shared__ int ldeg[RPB];
  const int t = threadIdx.x, c = t & 127, p = t >> 7;
  const int b = blockIdx.x;

  // init x,r,d0 for my rows + stage CSR to LDS (once)
#pragma unroll
  for (int k = 0; k < RPB; ++k) {
    int i = b + GBLK * k;
    int dg = degG[i];
    if (t == 0) ldeg[k] = dg;
    for (int s = t; s < dg; s += 512) {
      lcol[k * CAP + s] = colG[(size_t)i * CAP + s];
      lval[k * CAP + s] = svalG[(size_t)i * CAP + s];
    }
    if (p == 0) {
      float y = 0.f;
      if (i < NSUP) y = (slab[i] == c) ? 1.f : 0.f;
      size_t o = (size_t)i * NCLS + c;
      x[o] = 0.f; r[o] = y; d0[o] = y;
    }
  }
  __syncthreads();
  const float ahat = alpha[0];
  grid.sync();

  float* dc = d0; float* dn = d1;
  for (int it = 0; it < TITER; ++it) {
    float rho = rho_tab[it], rhon = rho_tab[it + 1];
    float cc1 = rhon * rho, cc2 = 2.f * rhon / ahat;
#pragma unroll
    for (int k = 0; k < RPB; ++k) {
      int i = b + GBLK * k;
      int dg = ldeg[k];
      const int* lc = lcol + k * CAP;
      const float* lv = lval + k * CAP;
      float acc = 0.f;
      int s = p;
      for (; s + 12 < dg; s += 16) {  // 4 partitions x 4-deep unroll
        int j0 = lc[s], j1 = lc[s + 4], j2 = lc[s + 8], j3 = lc[s + 12];
        float v0 = lv[s], v1 = lv[s + 4], v2 = lv[s + 8], v3 = lv[s + 12];
        float a0 = dc[(size_t)j0 * NCLS + c];
        float a1 = dc[(size_t)j1 * NCLS + c];
        float a2 = dc[(size_t)j2 * NCLS + c];
        float a3 = dc[(size_t)j3 * NCLS + c];
        acc = fmaf(v0, a0, acc); acc = fmaf(v1, a1, acc);
        acc = fmaf(v2, a2, acc); acc = fmaf(v3, a3, acc);
      }
      for (; s < dg; s += 4) acc = fmaf(lv[s], dc[(size_t)lc[s] * NCLS + c], acc);
      partial[t] = acc;
      __syncthreads();
      if (p == 0) {
        float ax = partial[c] + partial[128 + c] + partial[256 + c] + partial[384 + c];
        size_t o = (size_t)i * NCLS + c;
        float di = dc[o];
        float q = di - ahat * ax;          // q = (A d)_ic,  A = I - alpha*S
        x[o] += di;
        float rv = r[o] - q; r[o] = rv;
        dn[o] = cc1 * di + cc2 * rv;
      }
      __syncthreads();
    }
    grid.sync();
    float* tmp = dc; dc = dn; dn = tmp;
  }

  // loss + acc tail: wave w (w<5) handles row b + 512*w, 2 classes/lane
  int wv = t >> 6, lane = t & 63;
  if (wv < RPB) {
    int i = b + GBLK * wv;
    int c0 = 2 * lane;
    float2 f = *(const float2*)(x + (size_t)i * NCLS + c0);
    float mx = fmaxf(f.x, f.y);
    for (int o2 = 32; o2 > 0; o2 >>= 1) mx = fmaxf(mx, __shfl_xor(mx, o2, 64));
    float se = expf(f.x - mx) + expf(f.y - mx);
    for (int o2 = 32; o2 > 0; o2 >>= 1) se += __shfl_xor(se, o2, 64);
    float lse = mx + logf(se);
    int gt = (i < NSUP) ? slab[i] : qlab[i - NSUP];
    float fg = ((c0 == gt) ? f.x : 0.f) + ((c0 + 1 == gt) ? f.y : 0.f);
    for (int o2 = 32; o2 > 0; o2 >>= 1) fg += __shfl_xor(fg, o2, 64);
    if (lane == 0) atomicAdd(lossSum, fg - lse);
    if (i >= NSUP) {
      float bvv; int bc;
      if (f.y > f.x) { bvv = f.y; bc = c0 + 1; } else { bvv = f.x; bc = c0; }
      unsigned long long packed =
          (((unsigned long long)sortkey(bvv)) << 32) | (unsigned long long)(unsigned)(127 - bc);
      for (int o2 = 32; o2 > 0; o2 >>= 1) {
        unsigned long long o = __shfl_xor(packed, o2, 64);
        if (o > packed) packed = o;
      }
      int cw = 127 - (int)(packed & 0xFFFFFFFFull);
      if (lane == 0 && cw == qlab[i - NSUP]) atomicAdd(accCnt, 1);
    }
  }
  grid.sync();
  if (b == 0 && t == 0) {
    out[0] = -lossSum[0] / (float)N;
    out[1] = (float)accCnt[0] / (float)NQ;
  }
}

// ---------- launch ----------
extern "C" void kernel_launch(void* const* d_in, const int* in_sizes, int n_in,
                              void* d_out, int out_size, void* d_ws, size_t ws_size,
                              hipStream_t stream) {
  const float* feats = (const float*)d_in[0];
  const float* alpha = (const float*)d_in[1];
  const int* slab = (const int*)d_in[2];
  const int* qlab = (const int*)d_in[3];
  float* out = (float*)d_out;
  char* ws = (char*)d_ws;

  // ws layout (bytes). C region (26,214,400) is reused for x/r/d0/d1 after CSR build.
  float* C      = (float*)(ws + 0);
  float* x      = (float*)(ws + 0);
  float* r      = (float*)(ws + 1310720);
  float* d0     = (float*)(ws + 2621440);
  float* d1     = (float*)(ws + 3932160);
  unsigned* M   = (unsigned*)(ws + 26214400);          // 819,200 B bitmask
  float* ctrl   = (float*)(ws + 27033600);             // 1,024 B: lossSum, accCnt, rho_tab
  float* lossSum = ctrl;
  int* accCnt   = (int*)(ctrl + 1);
  float* rho_tab = ctrl + 4;                           // 128 floats
  float* sq     = (float*)(ws + 27034624);
  float* dsi    = (float*)(ws + 27044864);
  int* degG     = (int*)(ws + 27055104);
  unsigned short* fb = (unsigned short*)(ws + 27065344);          // 41,943,040 B
  int* colG     = (int*)(ws + 27065344);               // overlays fb after GEMM
  float* svalG  = (float*)(ws + 27065344 + 10485760);  // overlays fb after GEMM
  // total ws required: 69,008,384 bytes

  hipMemsetAsync(ws + 26214400, 0, 820224, stream);    // M + ctrl
  k_prep<<<N, 256, 0, stream>>>(feats, fb, sq, alpha, rho_tab);
  k_gemm<<<210, 256, 0, stream>>>(fb, C);              // lower-tri tiles only
  k_topk<<<N / 4, 256, 0, stream>>>(C, sq, M);
  k_csr<<<N, 256, 0, stream>>>(C, sq, M, colG, svalG, degG, dsi);
  k_scale<<<N / 4, 256, 0, stream>>>(colG, svalG, degG, dsi);
  void* args[] = {&colG, &svalG, &degG, &rho_tab, &alpha, &x, &r, &d0, &d1,
                  &slab, &qlab, &lossSum, &accCnt, &out};
  hipLaunchCooperativeKernel((void*)k_fused, dim3(GBLK), dim3(512), args, 0, stream);
}

// Round 4
// 870.965 us; speedup vs baseline: 6.6164x; 6.6164x over previous
//
#include <hip/hip_runtime.h>
#include <stdint.h>

#define N 2560
#define NSUP 640
#define NQ 1920
#define NCLS 128
#define DF 8192
#define CAP 1024
#define TITER 40
#define EPSF 2.220446049250313e-16f

typedef __attribute__((ext_vector_type(8))) short bf16x8;
typedef __attribute__((ext_vector_type(4))) float f32x4;

// ---------- helpers ----------
__device__ __forceinline__ unsigned short f2bf(float f) {
  unsigned u = __float_as_uint(f);
  return (unsigned short)((u + 0x7FFFu + ((u >> 16) & 1u)) >> 16);  // RNE
}
__device__ __forceinline__ unsigned sortkey(float f) {
  unsigned u = __float_as_uint(f);
  return (u & 0x80000000u) ? ~u : (u | 0x80000000u);
}
__device__ __forceinline__ void load_lds16(const void* g, void* l) {
  __builtin_amdgcn_global_load_lds((const __attribute__((address_space(1))) void*)g,
                                   (__attribute__((address_space(3))) void*)l, 16, 0, 0);
}

// ---------- 1. fp32 -> bf16 copy + row sumsq + rho table ----------
__global__ void k_prep(const float* __restrict__ feats, unsigned short* __restrict__ fb,
                       float* __restrict__ sq, const float* __restrict__ alpha,
                       float* __restrict__ rho_tab) {
  int i = blockIdx.x, t = threadIdx.x;
  const float4* src = (const float4*)(feats + (size_t)i * DF);
  ushort4* dst = (ushort4*)(fb + (size_t)i * DF);
  float s = 0.f;
#pragma unroll
  for (int it = 0; it < 8; ++it) {
    float4 v = src[it * 256 + t];
    s = fmaf(v.x, v.x, s); s = fmaf(v.y, v.y, s);
    s = fmaf(v.z, v.z, s); s = fmaf(v.w, v.w, s);
    ushort4 o; o.x = f2bf(v.x); o.y = f2bf(v.y); o.z = f2bf(v.z); o.w = f2bf(v.w);
    dst[it * 256 + t] = o;
  }
  __shared__ float red[256];
  red[t] = s; __syncthreads();
  for (int o = 128; o > 0; o >>= 1) { if (t < o) red[t] += red[t + o]; __syncthreads(); }
  if (t == 0) sq[i] = red[0];
  if (i == 0 && t == 0) {  // Chebyshev rho recurrence (theta=1, delta=alpha)
    float a = alpha[0];
    float rho = a; rho_tab[0] = rho;
    for (int k2 = 1; k2 < 128; ++k2) { rho = 1.f / (2.f / a - rho); rho_tab[k2] = rho; }
  }
}

// ---------- 2. C = fb @ fb^T, symmetric-half: 210 lower-tri 128x128 tiles ----------
__global__ __launch_bounds__(256, 2) void k_gemm(const unsigned short* __restrict__ fb,
                                                 float* __restrict__ C) {
  __shared__ __align__(16) unsigned short As[128 * 32];
  __shared__ __align__(16) unsigned short Bs[128 * 32];
  int bid = blockIdx.x;
  int bx = (int)((sqrtf(8.0f * (float)bid + 1.0f) - 1.0f) * 0.5f);
  while ((bx + 1) * (bx + 2) / 2 <= bid) ++bx;
  while (bx * (bx + 1) / 2 > bid) --bx;
  int by = bid - bx * (bx + 1) / 2;            // by <= bx
  const int rA = by * 128, rB = bx * 128;
  const int t = threadIdx.x, w = t >> 6, l = t & 63;
  const int q = l >> 4, m = l & 15;
  const int wr = w >> 1, wc = w & 1;
  f32x4 acc[4][4];
#pragma unroll
  for (int a2 = 0; a2 < 4; ++a2)
#pragma unroll
    for (int b2 = 0; b2 < 4; ++b2) acc[a2][b2] = (f32x4){0.f, 0.f, 0.f, 0.f};

  const int c0 = (w * 2 + 0) * 64 + l;   // chunk ids (16B chunks of the 8KB tile)
  const int c1 = (w * 2 + 1) * 64 + l;
  const int r0 = c0 >> 2, o0 = (c0 & 3) * 8;
  const int r1 = c1 >> 2, o1 = (c1 & 3) * 8;
  char* lA0 = (char*)As + (w * 2 + 0) * 1024;
  char* lA1 = (char*)As + (w * 2 + 1) * 1024;
  char* lB0 = (char*)Bs + (w * 2 + 0) * 1024;
  char* lB1 = (char*)Bs + (w * 2 + 1) * 1024;

  for (int k0 = 0; k0 < DF; k0 += 32) {
    load_lds16(fb + (size_t)(rA + r0) * DF + k0 + o0, lA0);
    load_lds16(fb + (size_t)(rA + r1) * DF + k0 + o1, lA1);
    load_lds16(fb + (size_t)(rB + r0) * DF + k0 + o0, lB0);
    load_lds16(fb + (size_t)(rB + r1) * DF + k0 + o1, lB1);
    asm volatile("s_waitcnt vmcnt(0)" ::: "memory");
    __syncthreads();
    bf16x8 af[4], bv[4];
#pragma unroll
    for (int im = 0; im < 4; ++im)
      af[im] = *(const bf16x8*)(As + (wr * 64 + im * 16 + m) * 32 + q * 8);
#pragma unroll
    for (int in = 0; in < 4; ++in)
      bv[in] = *(const bf16x8*)(Bs + (wc * 64 + in * 16 + m) * 32 + q * 8);
#pragma unroll
    for (int im = 0; im < 4; ++im)
#pragma unroll
      for (int in = 0; in < 4; ++in)
        acc[im][in] = __builtin_amdgcn_mfma_f32_16x16x32_bf16(af[im], bv[in], acc[im][in], 0, 0, 0);
    __syncthreads();
  }
#pragma unroll
  for (int im = 0; im < 4; ++im) {
    int row0 = rA + wr * 64 + im * 16 + q * 4;
#pragma unroll
    for (int in = 0; in < 4; ++in) {
      int col = rB + wc * 64 + in * 16 + m;
#pragma unroll
      for (int rg = 0; rg < 4; ++rg) {
        C[(size_t)(row0 + rg) * N + col] = acc[im][in][rg];
        C[(size_t)col * N + row0 + rg] = acc[im][in][rg];   // symmetric image
      }
    }
  }
}

// ---------- 3. per-row top-20 (key = 2*C - sq_j, ties -> lower idx), set bits ----------
__global__ void k_topk(const float* __restrict__ C, const float* __restrict__ sq,
                       unsigned* __restrict__ M) {
  int i = blockIdx.x * 4 + (threadIdx.x >> 6);
  int lane = threadIdx.x & 63;
  const float* Crow = C + (size_t)i * N;
  unsigned kk[40];
#pragma unroll
  for (int s = 0; s < 40; ++s) {
    int j = lane + (s << 6);
    kk[s] = sortkey(2.f * Crow[j] - sq[j]);
  }
  unsigned long long removed = 0ull;
  unsigned myj = 0u;
  for (int t = 0; t < 20; ++t) {
    unsigned bk = 0u; int bs = -1;
#pragma unroll
    for (int s = 0; s < 40; ++s)
      if (!((removed >> s) & 1ull) && kk[s] > bk) { bk = kk[s]; bs = s; }
    unsigned long long packed = (bs < 0) ? 0ull
        : ((((unsigned long long)bk) << 32) |
           (unsigned long long)(0xFFFFFFFFu - (unsigned)(lane + (bs << 6))));
#pragma unroll
    for (int off2 = 32; off2 > 0; off2 >>= 1) {
      unsigned long long o = __shfl_xor(packed, off2, 64);
      if (o > packed) packed = o;
    }
    unsigned jw = 0xFFFFFFFFu - (unsigned)(packed & 0xFFFFFFFFull);
    if ((int)(jw & 63u) == lane) removed |= 1ull << (jw >> 6);
    if (t == lane) myj = jw;
  }
  if (lane < 20) atomicOr(&M[(size_t)i * 80 + (myj >> 5)], 1u << (myj & 31u));
}

// ---------- 4. symmetrize mask, build padded CSR of W, row sums D, dsi ----------
__global__ void k_csr(const float* __restrict__ C, const float* __restrict__ sq,
                      const unsigned* __restrict__ M, int* __restrict__ colG,
                      float* __restrict__ svalG, int* __restrict__ degG,
                      float* __restrict__ dsi) {
  int i = blockIdx.x, t = threadIdx.x;
  __shared__ unsigned Mrow[80];
  __shared__ int degs;
  __shared__ int cols[CAP];
  __shared__ float wvs[CAP];
  __shared__ float red[256];
  if (t < 80) Mrow[t] = M[(size_t)i * 80 + t];
  if (t == 0) degs = 0;
  __syncthreads();
  const float* Crow = C + (size_t)i * N;
  float sqi = sq[i];
  int iw = i >> 5; unsigned ib = 1u << (i & 31);
  float dsum = 0.f;
#pragma unroll
  for (int s = 0; s < 10; ++s) {
    int j = t + (s << 8);
    unsigned mij = (Mrow[j >> 5] >> (j & 31)) & 1u;
    unsigned mji = M[(size_t)j * 80 + iw] & ib;
    if (mij | (mji != 0u)) {
      float wv = expf((2.f * Crow[j] - sqi - sq[j]) * (1.f / 16384.f));
      int sl = atomicAdd(&degs, 1);
      if (sl < CAP) { cols[sl] = j; wvs[sl] = wv; }
      dsum += wv;
    }
  }
  red[t] = dsum; __syncthreads();
  for (int o = 128; o > 0; o >>= 1) { if (t < o) red[t] += red[t + o]; __syncthreads(); }
  if (t == 0) {
    degG[i] = degs > CAP ? CAP : degs;
    dsi[i] = 1.f / sqrtf(red[0] + EPSF);
  }
  __syncthreads();
  int dgc = degs > CAP ? CAP : degs;
  for (int sl = t; sl < dgc; sl += 256) {
    colG[(size_t)i * CAP + sl] = cols[sl];
    svalG[(size_t)i * CAP + sl] = wvs[sl];
  }
}

// ---------- 5. S edge values: w *= dsi_i * dsi_j ----------
__global__ void k_scale(const int* __restrict__ colG, float* __restrict__ svalG,
                        const int* __restrict__ degG, const float* __restrict__ dsi) {
  int i = blockIdx.x * 4 + (threadIdx.x >> 6);
  int lane = threadIdx.x & 63;
  float di = dsi[i];
  int dg = degG[i];
  for (int s = lane; s < dg; s += 64)
    svalG[(size_t)i * CAP + s] *= di * dsi[colG[(size_t)i * CAP + s]];
}

// ---------- 6a. Chebyshev init: x=0, r=d0=y ----------
__global__ void k_cginit(const int* __restrict__ slab, float* __restrict__ x,
                         float* __restrict__ r, float* __restrict__ d0) {
  int i = blockIdx.x * 4 + (threadIdx.x >> 6);
  int lane = threadIdx.x & 63;
  int c0 = 2 * lane;
  float y0 = 0.f, y1 = 0.f;
  if (i < NSUP) {
    int lbl = slab[i];
    y0 = (lbl == c0) ? 1.f : 0.f;
    y1 = (lbl == c0 + 1) ? 1.f : 0.f;
  }
  size_t o = (size_t)i * NCLS + c0;
  x[o] = 0.f; x[o + 1] = 0.f;
  r[o] = y0;  r[o + 1] = y1;
  d0[o] = y0; d0[o + 1] = y1;
}

// ---------- 6b. one Chebyshev iteration (A = I - alpha*S) ----------
// Block per row, 512 threads: g = t&31 (class group of 4), p = t>>5 (16 edge
// partitions). CSR staged to LDS padded to x128 (zero-weight dummies) so the
// gather loop is a clean 8-deep unroll: 128 float4 gathers in flight per row.
__global__ __launch_bounds__(512) void k_cheby(const int* __restrict__ colG,
                        const float* __restrict__ svalG,
                        const int* __restrict__ degG, const float* __restrict__ rho_tab,
                        const float* __restrict__ alpha, float* __restrict__ x,
                        float* __restrict__ r, const float* __restrict__ dcur,
                        float* __restrict__ dnxt, int it) {
  int i = blockIdx.x;
  int t = threadIdx.x;
  int g4 = (t & 31) << 2, p = t >> 5;
  __shared__ int lcol[CAP];
  __shared__ float lval[CAP];
  __shared__ float4 partial[512];
  int dg = degG[i];
  int dgp = (dg + 127) & ~127;           // pad to multiple of 128
  for (int s = t; s < dgp; s += 512) {
    bool live = s < dg;
    lcol[s] = live ? colG[(size_t)i * CAP + s] : 0;
    lval[s] = live ? svalG[(size_t)i * CAP + s] : 0.f;
  }
  __syncthreads();
  float4 acc = make_float4(0.f, 0.f, 0.f, 0.f);
  for (int s = p; s < dgp; s += 128) {   // 16 partitions x 8-deep unroll
    float4 a[8]; float v[8];
#pragma unroll
    for (int u = 0; u < 8; ++u) {
      int j = lcol[s + 16 * u];
      v[u] = lval[s + 16 * u];
      a[u] = *(const float4*)(dcur + (size_t)j * NCLS + g4);
    }
#pragma unroll
    for (int u = 0; u < 8; ++u) {
      acc.x = fmaf(v[u], a[u].x, acc.x);
      acc.y = fmaf(v[u], a[u].y, acc.y);
      acc.z = fmaf(v[u], a[u].z, acc.z);
      acc.w = fmaf(v[u], a[u].w, acc.w);
    }
  }
  partial[t] = acc;
  __syncthreads();
  for (int off = 256; off >= 32; off >>= 1) {
    if (t < off) {
      float4 o = partial[t + off];
      float4 m = partial[t];
      m.x += o.x; m.y += o.y; m.z += o.z; m.w += o.w;
      partial[t] = m;
    }
    __syncthreads();
  }
  if (t < 32) {                          // classes 4t..4t+3
    float4 ax = partial[t];
    float ahat = alpha[0];
    float rho = rho_tab[it], rhon = rho_tab[it + 1];
    float cc1 = rhon * rho, cc2 = 2.f * rhon / ahat;
    size_t o = (size_t)i * NCLS + 4 * t;
    float4 di = *(const float4*)(dcur + o);
    float4 xv = *(float4*)(x + o);
    float4 rv = *(float4*)(r + o);
    float4 q;
    q.x = di.x - ahat * ax.x; q.y = di.y - ahat * ax.y;
    q.z = di.z - ahat * ax.z; q.w = di.w - ahat * ax.w;
    xv.x += di.x; xv.y += di.y; xv.z += di.z; xv.w += di.w;
    rv.x -= q.x; rv.y -= q.y; rv.z -= q.z; rv.w -= q.w;
    float4 dn;
    dn.x = cc1 * di.x + cc2 * rv.x; dn.y = cc1 * di.y + cc2 * rv.y;
    dn.z = cc1 * di.z + cc2 * rv.z; dn.w = cc1 * di.w + cc2 * rv.w;
    *(float4*)(x + o) = xv;
    *(float4*)(r + o) = rv;
    *(float4*)(dnxt + o) = dn;
  }
}

// ---------- 7. loss + acc ----------
__global__ void k_loss(const float* __restrict__ F, const int* __restrict__ slab,
                       const int* __restrict__ qlab, float* __restrict__ lossSum,
                       int* __restrict__ accCnt) {
  int i = blockIdx.x * 4 + (threadIdx.x >> 6);
  int lane = threadIdx.x & 63;
  int c0 = 2 * lane;
  float2 f = *(const float2*)(F + (size_t)i * NCLS + c0);
  float mx = fmaxf(f.x, f.y);
  for (int o2 = 32; o2 > 0; o2 >>= 1) mx = fmaxf(mx, __shfl_xor(mx, o2, 64));
  float se = expf(f.x - mx) + expf(f.y - mx);
  for (int o2 = 32; o2 > 0; o2 >>= 1) se += __shfl_xor(se, o2, 64);
  float lse = mx + logf(se);
  int gt = (i < NSUP) ? slab[i] : qlab[i - NSUP];
  float fg = ((c0 == gt) ? f.x : 0.f) + ((c0 + 1 == gt) ? f.y : 0.f);
  for (int o2 = 32; o2 > 0; o2 >>= 1) fg += __shfl_xor(fg, o2, 64);
  if (lane == 0) atomicAdd(lossSum, fg - lse);
  if (i >= NSUP) {
    float bvv; int bc;
    if (f.y > f.x) { bvv = f.y; bc = c0 + 1; } else { bvv = f.x; bc = c0; }
    unsigned long long packed =
        (((unsigned long long)sortkey(bvv)) << 32) | (unsigned long long)(unsigned)(127 - bc);
    for (int o2 = 32; o2 > 0; o2 >>= 1) {
      unsigned long long o = __shfl_xor(packed, o2, 64);
      if (o > packed) packed = o;
    }
    int cw = 127 - (int)(packed & 0xFFFFFFFFull);
    if (lane == 0 && cw == qlab[i - NSUP]) atomicAdd(accCnt, 1);
  }
}

// ---------- 8. finalize ----------
__global__ void k_final(const float* __restrict__ lossSum, const int* __restrict__ accCnt,
                        float* __restrict__ out) {
  out[0] = -lossSum[0] / (float)N;
  out[1] = (float)accCnt[0] / (float)NQ;
}

// ---------- launch ----------
extern "C" void kernel_launch(void* const* d_in, const int* in_sizes, int n_in,
                              void* d_out, int out_size, void* d_ws, size_t ws_size,
                              hipStream_t stream) {
  const float* feats = (const float*)d_in[0];
  const float* alpha = (const float*)d_in[1];
  const int* slab = (const int*)d_in[2];
  const int* qlab = (const int*)d_in[3];
  float* out = (float*)d_out;
  char* ws = (char*)d_ws;

  // ws layout (bytes). C region (26,214,400) is reused for x/r/d0/d1 after CSR build.
  float* C      = (float*)(ws + 0);
  float* x      = (float*)(ws + 0);
  float* r      = (float*)(ws + 1310720);
  float* d0     = (float*)(ws + 2621440);
  float* d1     = (float*)(ws + 3932160);
  unsigned* M   = (unsigned*)(ws + 26214400);          // 819,200 B bitmask
  float* ctrl   = (float*)(ws + 27033600);             // 1,024 B: lossSum, accCnt, rho_tab
  float* lossSum = ctrl;
  int* accCnt   = (int*)(ctrl + 1);
  float* rho_tab = ctrl + 4;                           // 128 floats
  float* sq     = (float*)(ws + 27034624);
  float* dsi    = (float*)(ws + 27044864);
  int* degG     = (int*)(ws + 27055104);
  unsigned short* fb = (unsigned short*)(ws + 27065344);          // 41,943,040 B
  int* colG     = (int*)(ws + 27065344);               // overlays fb after GEMM
  float* svalG  = (float*)(ws + 27065344 + 10485760);  // overlays fb after GEMM
  // total ws required: 69,008,384 bytes

  hipMemsetAsync(ws + 26214400, 0, 820224, stream);    // M + ctrl
  k_prep<<<N, 256, 0, stream>>>(feats, fb, sq, alpha, rho_tab);
  k_gemm<<<210, 256, 0, stream>>>(fb, C);              // lower-tri tiles only
  k_topk<<<N / 4, 256, 0, stream>>>(C, sq, M);
  k_csr<<<N, 256, 0, stream>>>(C, sq, M, colG, svalG, degG, dsi);
  k_scale<<<N / 4, 256, 0, stream>>>(colG, svalG, degG, dsi);
  k_cginit<<<N / 4, 256, 0, stream>>>(slab, x, r, d0);
  for (int it = 0; it < TITER; ++it) {
    const float* dc = (it & 1) ? d1 : d0;
    float* dn = (it & 1) ? d0 : d1;
    k_cheby<<<N, 512, 0, stream>>>(colG, svalG, degG, rho_tab, alpha, x, r, dc, dn, it);
  }
  k_loss<<<N / 4, 256, 0, stream>>>(x, slab, qlab, lossSum, accCnt);
  k_final<<<1, 1, 0, stream>>>(lossSum, accCnt, out);
}

// Round 5
// 693.012 us; speedup vs baseline: 8.3153x; 1.2568x over previous
//
#include <hip/hip_runtime.h>
#include <stdint.h>

#define N 2560
#define NSUP 640
#define NQ 1920
#define NCLS 128
#define DF 8192
#define CAP 1024
#define TITER 32
#define EPSF 2.220446049250313e-16f

typedef __attribute__((ext_vector_type(8))) short bf16x8;
typedef __attribute__((ext_vector_type(4))) float f32x4;

// ---------- helpers ----------
__device__ __forceinline__ unsigned short f2bf(float f) {
  unsigned u = __float_as_uint(f);
  return (unsigned short)((u + 0x7FFFu + ((u >> 16) & 1u)) >> 16);  // RNE
}
__device__ __forceinline__ float bf2f(unsigned short h) {
  return __uint_as_float(((unsigned)h) << 16);
}
__device__ __forceinline__ unsigned sortkey(float f) {
  unsigned u = __float_as_uint(f);
  return (u & 0x80000000u) ? ~u : (u | 0x80000000u);
}
__device__ __forceinline__ void load_lds16(const void* g, void* l) {
  __builtin_amdgcn_global_load_lds((const __attribute__((address_space(1))) void*)g,
                                   (__attribute__((address_space(3))) void*)l, 16, 0, 0);
}

// ---------- 1. fp32 -> bf16 copy + row sumsq + rho table ----------
__global__ void k_prep(const float* __restrict__ feats, unsigned short* __restrict__ fb,
                       float* __restrict__ sq, const float* __restrict__ alpha,
                       float* __restrict__ rho_tab) {
  int i = blockIdx.x, t = threadIdx.x;
  const float4* src = (const float4*)(feats + (size_t)i * DF);
  ushort4* dst = (ushort4*)(fb + (size_t)i * DF);
  float s = 0.f;
#pragma unroll
  for (int it = 0; it < 8; ++it) {
    float4 v = src[it * 256 + t];
    s = fmaf(v.x, v.x, s); s = fmaf(v.y, v.y, s);
    s = fmaf(v.z, v.z, s); s = fmaf(v.w, v.w, s);
    ushort4 o; o.x = f2bf(v.x); o.y = f2bf(v.y); o.z = f2bf(v.z); o.w = f2bf(v.w);
    dst[it * 256 + t] = o;
  }
  __shared__ float red[256];
  red[t] = s; __syncthreads();
  for (int o = 128; o > 0; o >>= 1) { if (t < o) red[t] += red[t + o]; __syncthreads(); }
  if (t == 0) sq[i] = red[0];
  if (i == 0 && t == 0) {  // Chebyshev rho recurrence (theta=1, delta=alpha)
    float a = alpha[0];
    float rho = a; rho_tab[0] = rho;
    for (int k2 = 1; k2 < 128; ++k2) { rho = 1.f / (2.f / a - rho); rho_tab[k2] = rho; }
  }
}

// ---------- 2. C = fb @ fb^T, symmetric-half + split-K x2, bf16 output ----------
// 420 blocks: bid<210 -> K [0,4096) into C0; else K [4096,8192) into C1.
__global__ __launch_bounds__(256, 2) void k_gemm(const unsigned short* __restrict__ fb,
                                                 unsigned short* __restrict__ C0,
                                                 unsigned short* __restrict__ C1) {
  __shared__ __align__(16) unsigned short As[128 * 32];
  __shared__ __align__(16) unsigned short Bs[128 * 32];
  int bid = blockIdx.x;
  int ks = bid >= 210;
  int tid2 = bid - 210 * ks;
  unsigned short* Cd = ks ? C1 : C0;
  const int kbase = ks << 12;
  int bx = (int)((sqrtf(8.0f * (float)tid2 + 1.0f) - 1.0f) * 0.5f);
  while ((bx + 1) * (bx + 2) / 2 <= tid2) ++bx;
  while (bx * (bx + 1) / 2 > tid2) --bx;
  int by = tid2 - bx * (bx + 1) / 2;           // by <= bx
  const int rA = by * 128, rB = bx * 128;
  const int t = threadIdx.x, w = t >> 6, l = t & 63;
  const int q = l >> 4, m = l & 15;
  const int wr = w >> 1, wc = w & 1;
  f32x4 acc[4][4];
#pragma unroll
  for (int a2 = 0; a2 < 4; ++a2)
#pragma unroll
    for (int b2 = 0; b2 < 4; ++b2) acc[a2][b2] = (f32x4){0.f, 0.f, 0.f, 0.f};

  const int c0 = (w * 2 + 0) * 64 + l;   // chunk ids (16B chunks of the 8KB tile)
  const int c1 = (w * 2 + 1) * 64 + l;
  const int r0 = c0 >> 2, o0 = (c0 & 3) * 8;
  const int r1 = c1 >> 2, o1 = (c1 & 3) * 8;
  char* lA0 = (char*)As + (w * 2 + 0) * 1024;
  char* lA1 = (char*)As + (w * 2 + 1) * 1024;
  char* lB0 = (char*)Bs + (w * 2 + 0) * 1024;
  char* lB1 = (char*)Bs + (w * 2 + 1) * 1024;

  for (int k0 = kbase; k0 < kbase + 4096; k0 += 32) {
    load_lds16(fb + (size_t)(rA + r0) * DF + k0 + o0, lA0);
    load_lds16(fb + (size_t)(rA + r1) * DF + k0 + o1, lA1);
    load_lds16(fb + (size_t)(rB + r0) * DF + k0 + o0, lB0);
    load_lds16(fb + (size_t)(rB + r1) * DF + k0 + o1, lB1);
    asm volatile("s_waitcnt vmcnt(0)" ::: "memory");
    __syncthreads();
    bf16x8 af[4], bv[4];
#pragma unroll
    for (int im = 0; im < 4; ++im)
      af[im] = *(const bf16x8*)(As + (wr * 64 + im * 16 + m) * 32 + q * 8);
#pragma unroll
    for (int in = 0; in < 4; ++in)
      bv[in] = *(const bf16x8*)(Bs + (wc * 64 + in * 16 + m) * 32 + q * 8);
#pragma unroll
    for (int im = 0; im < 4; ++im)
#pragma unroll
      for (int in = 0; in < 4; ++in)
        acc[im][in] = __builtin_amdgcn_mfma_f32_16x16x32_bf16(af[im], bv[in], acc[im][in], 0, 0, 0);
    __syncthreads();
  }
#pragma unroll
  for (int im = 0; im < 4; ++im) {
    int row0 = rA + wr * 64 + im * 16 + q * 4;
#pragma unroll
    for (int in = 0; in < 4; ++in) {
      int col = rB + wc * 64 + in * 16 + m;
#pragma unroll
      for (int rg = 0; rg < 4; ++rg) {
        unsigned short h = f2bf(acc[im][in][rg]);
        Cd[(size_t)(row0 + rg) * N + col] = h;
        Cd[(size_t)col * N + row0 + rg] = h;   // symmetric image
      }
    }
  }
}

// ---------- 3. per-row top-20 (key = 2*(C0+C1) - sq_j, ties -> lower idx) ----------
__global__ void k_topk(const unsigned short* __restrict__ C0,
                       const unsigned short* __restrict__ C1,
                       const float* __restrict__ sq, unsigned* __restrict__ M) {
  int i = blockIdx.x * 4 + (threadIdx.x >> 6);
  int lane = threadIdx.x & 63;
  const unsigned short* r0 = C0 + (size_t)i * N;
  const unsigned short* r1 = C1 + (size_t)i * N;
  unsigned kk[40];
#pragma unroll
  for (int s = 0; s < 40; ++s) {
    int j = lane + (s << 6);
    float c = bf2f(r0[j]) + bf2f(r1[j]);
    kk[s] = sortkey(2.f * c - sq[j]);
  }
  unsigned long long removed = 0ull;
  unsigned myj = 0u;
  for (int t = 0; t < 20; ++t) {
    unsigned bk = 0u; int bs = -1;
#pragma unroll
    for (int s = 0; s < 40; ++s)
      if (!((removed >> s) & 1ull) && kk[s] > bk) { bk = kk[s]; bs = s; }
    unsigned long long packed = (bs < 0) ? 0ull
        : ((((unsigned long long)bk) << 32) |
           (unsigned long long)(0xFFFFFFFFu - (unsigned)(lane + (bs << 6))));
#pragma unroll
    for (int off2 = 32; off2 > 0; off2 >>= 1) {
      unsigned long long o = __shfl_xor(packed, off2, 64);
      if (o > packed) packed = o;
    }
    unsigned jw = 0xFFFFFFFFu - (unsigned)(packed & 0xFFFFFFFFull);
    if ((int)(jw & 63u) == lane) removed |= 1ull << (jw >> 6);
    if (t == lane) myj = jw;
  }
  if (lane < 20) atomicOr(&M[(size_t)i * 80 + (myj >> 5)], 1u << (myj & 31u));
}

// ---------- 4. symmetrize mask, build padded CSR of W, row sums D, dsi ----------
__global__ void k_csr(const unsigned short* __restrict__ C0,
                      const unsigned short* __restrict__ C1,
                      const float* __restrict__ sq,
                      const unsigned* __restrict__ M, int* __restrict__ colG,
                      float* __restrict__ svalG, int* __restrict__ degG,
                      float* __restrict__ dsi) {
  int i = blockIdx.x, t = threadIdx.x;
  __shared__ unsigned Mrow[80];
  __shared__ int degs;
  __shared__ int cols[CAP];
  __shared__ float wvs[CAP];
  __shared__ float red[256];
  if (t < 80) Mrow[t] = M[(size_t)i * 80 + t];
  if (t == 0) degs = 0;
  __syncthreads();
  const unsigned short* r0c = C0 + (size_t)i * N;
  const unsigned short* r1c = C1 + (size_t)i * N;
  float sqi = sq[i];
  int iw = i >> 5; unsigned ib = 1u << (i & 31);
  float dsum = 0.f;
#pragma unroll
  for (int s = 0; s < 10; ++s) {
    int j = t + (s << 8);
    unsigned mij = (Mrow[j >> 5] >> (j & 31)) & 1u;
    unsigned mji = M[(size_t)j * 80 + iw] & ib;
    if (mij | (mji != 0u)) {
      float c = bf2f(r0c[j]) + bf2f(r1c[j]);
      float wv = expf((2.f * c - sqi - sq[j]) * (1.f / 16384.f));
      int sl = atomicAdd(&degs, 1);
      if (sl < CAP) { cols[sl] = j; wvs[sl] = wv; }
      dsum += wv;
    }
  }
  red[t] = dsum; __syncthreads();
  for (int o = 128; o > 0; o >>= 1) { if (t < o) red[t] += red[t + o]; __syncthreads(); }
  if (t == 0) {
    degG[i] = degs > CAP ? CAP : degs;
    dsi[i] = 1.f / sqrtf(red[0] + EPSF);
  }
  __syncthreads();
  int dgc = degs > CAP ? CAP : degs;
  for (int sl = t; sl < dgc; sl += 256) {
    colG[(size_t)i * CAP + sl] = cols[sl];
    svalG[(size_t)i * CAP + sl] = wvs[sl];
  }
}

// ---------- 5. merged: S edge scaling + Chebyshev init ----------
__global__ void k_scale_init(const int* __restrict__ colG, float* __restrict__ svalG,
                             const int* __restrict__ degG, const float* __restrict__ dsi,
                             const int* __restrict__ slab, float* __restrict__ x,
                             float* __restrict__ r, float* __restrict__ d0) {
  int i = blockIdx.x * 4 + (threadIdx.x >> 6);
  int lane = threadIdx.x & 63;
  float di = dsi[i];
  int dg = degG[i];
  for (int s = lane; s < dg; s += 64)
    svalG[(size_t)i * CAP + s] *= di * dsi[colG[(size_t)i * CAP + s]];
  int c0 = 2 * lane;
  float y0 = 0.f, y1 = 0.f;
  if (i < NSUP) {
    int lbl = slab[i];
    y0 = (lbl == c0) ? 1.f : 0.f;
    y1 = (lbl == c0 + 1) ? 1.f : 0.f;
  }
  size_t o = (size_t)i * NCLS + c0;
  x[o] = 0.f; x[o + 1] = 0.f;
  r[o] = y0;  r[o + 1] = y1;
  d0[o] = y0; d0[o + 1] = y1;
}

// ---------- 6. one Chebyshev iteration (A = I - alpha*S) ----------
// Block per row, 512 threads: g = t&31 (class group of 4), p = t>>5 (16 edge
// partitions). 8-deep unrolled main loop + 1-deep tail (no dummy gathers).
__global__ __launch_bounds__(512) void k_cheby(const int* __restrict__ colG,
                        const float* __restrict__ svalG,
                        const int* __restrict__ degG, const float* __restrict__ rho_tab,
                        const float* __restrict__ alpha, float* __restrict__ x,
                        float* __restrict__ r, const float* __restrict__ dcur,
                        float* __restrict__ dnxt, int it) {
  int i = blockIdx.x;
  int t = threadIdx.x;
  int g4 = (t & 31) << 2, p = t >> 5;
  __shared__ int lcol[CAP];
  __shared__ float lval[CAP];
  __shared__ float4 partial[512];
  int dg = degG[i];
  for (int s = t; s < dg; s += 512) {
    lcol[s] = colG[(size_t)i * CAP + s];
    lval[s] = svalG[(size_t)i * CAP + s];
  }
  __syncthreads();
  float4 acc = make_float4(0.f, 0.f, 0.f, 0.f);
  int s = p;
  for (; s + 112 < dg; s += 128) {       // full 8-deep rounds
    float4 a[8]; float v[8];
#pragma unroll
    for (int u = 0; u < 8; ++u) {
      int j = lcol[s + 16 * u];
      v[u] = lval[s + 16 * u];
      a[u] = *(const float4*)(dcur + (size_t)j * NCLS + g4);
    }
#pragma unroll
    for (int u = 0; u < 8; ++u) {
      acc.x = fmaf(v[u], a[u].x, acc.x);
      acc.y = fmaf(v[u], a[u].y, acc.y);
      acc.z = fmaf(v[u], a[u].z, acc.z);
      acc.w = fmaf(v[u], a[u].w, acc.w);
    }
  }
  for (; s < dg; s += 16) {              // tail
    int j = lcol[s];
    float v = lval[s];
    float4 a = *(const float4*)(dcur + (size_t)j * NCLS + g4);
    acc.x = fmaf(v, a.x, acc.x); acc.y = fmaf(v, a.y, acc.y);
    acc.z = fmaf(v, a.z, acc.z); acc.w = fmaf(v, a.w, acc.w);
  }
  partial[t] = acc;
  __syncthreads();
  for (int off = 256; off >= 32; off >>= 1) {
    if (t < off) {
      float4 o = partial[t + off];
      float4 m = partial[t];
      m.x += o.x; m.y += o.y; m.z += o.z; m.w += o.w;
      partial[t] = m;
    }
    __syncthreads();
  }
  if (t < 32) {                          // classes 4t..4t+3
    float4 ax = partial[t];
    float ahat = alpha[0];
    float rho = rho_tab[it], rhon = rho_tab[it + 1];
    float cc1 = rhon * rho, cc2 = 2.f * rhon / ahat;
    size_t o = (size_t)i * NCLS + 4 * t;
    float4 di = *(const float4*)(dcur + o);
    float4 xv = *(float4*)(x + o);
    float4 rv = *(float4*)(r + o);
    float4 q;
    q.x = di.x - ahat * ax.x; q.y = di.y - ahat * ax.y;
    q.z = di.z - ahat * ax.z; q.w = di.w - ahat * ax.w;
    xv.x += di.x; xv.y += di.y; xv.z += di.z; xv.w += di.w;
    rv.x -= q.x; rv.y -= q.y; rv.z -= q.z; rv.w -= q.w;
    float4 dn;
    dn.x = cc1 * di.x + cc2 * rv.x; dn.y = cc1 * di.y + cc2 * rv.y;
    dn.z = cc1 * di.z + cc2 * rv.z; dn.w = cc1 * di.w + cc2 * rv.w;
    *(float4*)(x + o) = xv;
    *(float4*)(r + o) = rv;
    *(float4*)(dnxt + o) = dn;
  }
}

// ---------- 7. loss + acc ----------
__global__ void k_loss(const float* __restrict__ F, const int* __restrict__ slab,
                       const int* __restrict__ qlab, float* __restrict__ lossSum,
                       int* __restrict__ accCnt) {
  int i = blockIdx.x * 4 + (threadIdx.x >> 6);
  int lane = threadIdx.x & 63;
  int c0 = 2 * lane;
  float2 f = *(const float2*)(F + (size_t)i * NCLS + c0);
  float mx = fmaxf(f.x, f.y);
  for (int o2 = 32; o2 > 0; o2 >>= 1) mx = fmaxf(mx, __shfl_xor(mx, o2, 64));
  float se = expf(f.x - mx) + expf(f.y - mx);
  for (int o2 = 32; o2 > 0; o2 >>= 1) se += __shfl_xor(se, o2, 64);
  float lse = mx + logf(se);
  int gt = (i < NSUP) ? slab[i] : qlab[i - NSUP];
  float fg = ((c0 == gt) ? f.x : 0.f) + ((c0 + 1 == gt) ? f.y : 0.f);
  for (int o2 = 32; o2 > 0; o2 >>= 1) fg += __shfl_xor(fg, o2, 64);
  if (lane == 0) atomicAdd(lossSum, fg - lse);
  if (i >= NSUP) {
    float bvv; int bc;
    if (f.y > f.x) { bvv = f.y; bc = c0 + 1; } else { bvv = f.x; bc = c0; }
    unsigned long long packed =
        (((unsigned long long)sortkey(bvv)) << 32) | (unsigned long long)(unsigned)(127 - bc);
    for (int o2 = 32; o2 > 0; o2 >>= 1) {
      unsigned long long o = __shfl_xor(packed, o2, 64);
      if (o > packed) packed = o;
    }
    int cw = 127 - (int)(packed & 0xFFFFFFFFull);
    if (lane == 0 && cw == qlab[i - NSUP]) atomicAdd(accCnt, 1);
  }
}

// ---------- 8. finalize ----------
__global__ void k_final(const float* __restrict__ lossSum, const int* __restrict__ accCnt,
                        float* __restrict__ out) {
  out[0] = -lossSum[0] / (float)N;
  out[1] = (float)accCnt[0] / (float)NQ;
}

// ---------- launch ----------
extern "C" void kernel_launch(void* const* d_in, const int* in_sizes, int n_in,
                              void* d_out, int out_size, void* d_ws, size_t ws_size,
                              hipStream_t stream) {
  const float* feats = (const float*)d_in[0];
  const float* alpha = (const float*)d_in[1];
  const int* slab = (const int*)d_in[2];
  const int* qlab = (const int*)d_in[3];
  float* out = (float*)d_out;
  char* ws = (char*)d_ws;

  // ws layout (bytes). C0/C1 (bf16, 13,107,200 each) reused for x/r/d0/d1 after CSR.
  unsigned short* C0 = (unsigned short*)(ws + 0);
  unsigned short* C1 = (unsigned short*)(ws + 13107200);
  float* x      = (float*)(ws + 0);
  float* r      = (float*)(ws + 1310720);
  float* d0     = (float*)(ws + 2621440);
  float* d1     = (float*)(ws + 3932160);
  unsigned* M   = (unsigned*)(ws + 26214400);          // 819,200 B bitmask
  float* ctrl   = (float*)(ws + 27033600);             // 1,024 B: lossSum, accCnt, rho_tab
  float* lossSum = ctrl;
  int* accCnt   = (int*)(ctrl + 1);
  float* rho_tab = ctrl + 4;                           // 128 floats
  float* sq     = (float*)(ws + 27034624);
  float* dsi    = (float*)(ws + 27044864);
  int* degG     = (int*)(ws + 27055104);
  unsigned short* fb = (unsigned short*)(ws + 27065344);          // 41,943,040 B
  int* colG     = (int*)(ws + 27065344);               // overlays fb after GEMM
  float* svalG  = (float*)(ws + 27065344 + 10485760);  // overlays fb after GEMM
  // total ws required: 69,008,384 bytes

  hipMemsetAsync(ws + 26214400, 0, 820224, stream);    // M + ctrl
  k_prep<<<N, 256, 0, stream>>>(feats, fb, sq, alpha, rho_tab);
  k_gemm<<<420, 256, 0, stream>>>(fb, C0, C1);         // lower-tri tiles, split-K x2
  k_topk<<<N / 4, 256, 0, stream>>>(C0, C1, sq, M);
  k_csr<<<N, 256, 0, stream>>>(C0, C1, sq, M, colG, svalG, degG, dsi);
  k_scale_init<<<N / 4, 256, 0, stream>>>(colG, svalG, degG, dsi, slab, x, r, d0);
  for (int it = 0; it < TITER; ++it) {
    const float* dc = (it & 1) ? d1 : d0;
    float* dn = (it & 1) ? d0 : d1;
    k_cheby<<<N, 512, 0, stream>>>(colG, svalG, degG, rho_tab, alpha, x, r, dc, dn, it);
  }
  k_loss<<<N / 4, 256, 0, stream>>>(x, slab, qlab, lossSum, accCnt);
  k_final<<<1, 1, 0, stream>>>(lossSum, accCnt, out);
}

// Round 6
// 574.208 us; speedup vs baseline: 10.0358x; 1.2069x over previous
//
#include <hip/hip_runtime.h>
#include <stdint.h>

#define N 2560
#define NSUP 640
#define NQ 1920
#define NCLS 128
#define DF 8192
#define CAP 1024
#define TITER 24
#define EPSF 2.220446049250313e-16f

typedef __attribute__((ext_vector_type(8))) short bf16x8;
typedef __attribute__((ext_vector_type(4))) float f32x4;

// ---------- helpers ----------
__device__ __forceinline__ unsigned short f2bf(float f) {
  unsigned u = __float_as_uint(f);
  return (unsigned short)((u + 0x7FFFu + ((u >> 16) & 1u)) >> 16);  // RNE
}
__device__ __forceinline__ float bf2f(unsigned short h) {
  return __uint_as_float(((unsigned)h) << 16);
}
__device__ __forceinline__ unsigned sortkey(float f) {
  unsigned u = __float_as_uint(f);
  return (u & 0x80000000u) ? ~u : (u | 0x80000000u);
}
__device__ __forceinline__ void load_lds16(const void* g, void* l) {
  __builtin_amdgcn_global_load_lds((const __attribute__((address_space(1))) void*)g,
                                   (__attribute__((address_space(3))) void*)l, 16, 0, 0);
}

// ---------- 1. fp32 -> bf16 copy + row sumsq + rho table ----------
__global__ void k_prep(const float* __restrict__ feats, unsigned short* __restrict__ fb,
                       float* __restrict__ sq, const float* __restrict__ alpha,
                       float* __restrict__ rho_tab) {
  int i = blockIdx.x, t = threadIdx.x;
  const float4* src = (const float4*)(feats + (size_t)i * DF);
  ushort4* dst = (ushort4*)(fb + (size_t)i * DF);
  float s = 0.f;
#pragma unroll
  for (int it = 0; it < 8; ++it) {
    float4 v = src[it * 256 + t];
    s = fmaf(v.x, v.x, s); s = fmaf(v.y, v.y, s);
    s = fmaf(v.z, v.z, s); s = fmaf(v.w, v.w, s);
    ushort4 o; o.x = f2bf(v.x); o.y = f2bf(v.y); o.z = f2bf(v.z); o.w = f2bf(v.w);
    dst[it * 256 + t] = o;
  }
  __shared__ float red[256];
  red[t] = s; __syncthreads();
  for (int o = 128; o > 0; o >>= 1) { if (t < o) red[t] += red[t + o]; __syncthreads(); }
  if (t == 0) sq[i] = red[0];
  if (i == 0 && t == 0) {  // Chebyshev rho recurrence (theta=1, delta=alpha)
    float a = alpha[0];
    float rho = a; rho_tab[0] = rho;
    for (int k2 = 1; k2 < 128; ++k2) { rho = 1.f / (2.f / a - rho); rho_tab[k2] = rho; }
  }
}

// ---------- 2. C = fb @ fb^T, symmetric-half + split-K x2, bf16 output ----------
// 420 blocks: bid<210 -> K [0,4096) into C0; else K [4096,8192) into C1.
__global__ __launch_bounds__(256, 2) void k_gemm(const unsigned short* __restrict__ fb,
                                                 unsigned short* __restrict__ C0,
                                                 unsigned short* __restrict__ C1) {
  __shared__ __align__(16) unsigned short As[128 * 32];
  __shared__ __align__(16) unsigned short Bs[128 * 32];
  int bid = blockIdx.x;
  int ks = bid >= 210;
  int tid2 = bid - 210 * ks;
  unsigned short* Cd = ks ? C1 : C0;
  const int kbase = ks << 12;
  int bx = (int)((sqrtf(8.0f * (float)tid2 + 1.0f) - 1.0f) * 0.5f);
  while ((bx + 1) * (bx + 2) / 2 <= tid2) ++bx;
  while (bx * (bx + 1) / 2 > tid2) --bx;
  int by = tid2 - bx * (bx + 1) / 2;           // by <= bx
  const int rA = by * 128, rB = bx * 128;
  const int t = threadIdx.x, w = t >> 6, l = t & 63;
  const int q = l >> 4, m = l & 15;
  const int wr = w >> 1, wc = w & 1;
  f32x4 acc[4][4];
#pragma unroll
  for (int a2 = 0; a2 < 4; ++a2)
#pragma unroll
    for (int b2 = 0; b2 < 4; ++b2) acc[a2][b2] = (f32x4){0.f, 0.f, 0.f, 0.f};

  const int c0 = (w * 2 + 0) * 64 + l;   // chunk ids (16B chunks of the 8KB tile)
  const int c1 = (w * 2 + 1) * 64 + l;
  const int r0 = c0 >> 2, o0 = (c0 & 3) * 8;
  const int r1 = c1 >> 2, o1 = (c1 & 3) * 8;
  char* lA0 = (char*)As + (w * 2 + 0) * 1024;
  char* lA1 = (char*)As + (w * 2 + 1) * 1024;
  char* lB0 = (char*)Bs + (w * 2 + 0) * 1024;
  char* lB1 = (char*)Bs + (w * 2 + 1) * 1024;

  for (int k0 = kbase; k0 < kbase + 4096; k0 += 32) {
    load_lds16(fb + (size_t)(rA + r0) * DF + k0 + o0, lA0);
    load_lds16(fb + (size_t)(rA + r1) * DF + k0 + o1, lA1);
    load_lds16(fb + (size_t)(rB + r0) * DF + k0 + o0, lB0);
    load_lds16(fb + (size_t)(rB + r1) * DF + k0 + o1, lB1);
    asm volatile("s_waitcnt vmcnt(0)" ::: "memory");
    __syncthreads();
    bf16x8 af[4], bv[4];
#pragma unroll
    for (int im = 0; im < 4; ++im)
      af[im] = *(const bf16x8*)(As + (wr * 64 + im * 16 + m) * 32 + q * 8);
#pragma unroll
    for (int in = 0; in < 4; ++in)
      bv[in] = *(const bf16x8*)(Bs + (wc * 64 + in * 16 + m) * 32 + q * 8);
#pragma unroll
    for (int im = 0; im < 4; ++im)
#pragma unroll
      for (int in = 0; in < 4; ++in)
        acc[im][in] = __builtin_amdgcn_mfma_f32_16x16x32_bf16(af[im], bv[in], acc[im][in], 0, 0, 0);
    __syncthreads();
  }
#pragma unroll
  for (int im = 0; im < 4; ++im) {
    int row0 = rA + wr * 64 + im * 16 + q * 4;
#pragma unroll
    for (int in = 0; in < 4; ++in) {
      int col = rB + wc * 64 + in * 16 + m;
#pragma unroll
      for (int rg = 0; rg < 4; ++rg) {
        unsigned short h = f2bf(acc[im][in][rg]);
        Cd[(size_t)(row0 + rg) * N + col] = h;
        Cd[(size_t)col * N + row0 + rg] = h;   // symmetric image
      }
    }
  }
}

// ---------- 3. per-row top-20 (key = 2*(C0+C1) - sq_j, ties -> lower idx) ----------
__global__ void k_topk(const unsigned short* __restrict__ C0,
                       const unsigned short* __restrict__ C1,
                       const float* __restrict__ sq, unsigned* __restrict__ M) {
  int i = blockIdx.x * 4 + (threadIdx.x >> 6);
  int lane = threadIdx.x & 63;
  const unsigned short* r0 = C0 + (size_t)i * N;
  const unsigned short* r1 = C1 + (size_t)i * N;
  unsigned kk[40];
#pragma unroll
  for (int s = 0; s < 40; ++s) {
    int j = lane + (s << 6);
    float c = bf2f(r0[j]) + bf2f(r1[j]);
    kk[s] = sortkey(2.f * c - sq[j]);
  }
  unsigned long long removed = 0ull;
  unsigned myj = 0u;
  for (int t = 0; t < 20; ++t) {
    unsigned bk = 0u; int bs = -1;
#pragma unroll
    for (int s = 0; s < 40; ++s)
      if (!((removed >> s) & 1ull) && kk[s] > bk) { bk = kk[s]; bs = s; }
    unsigned long long packed = (bs < 0) ? 0ull
        : ((((unsigned long long)bk) << 32) |
           (unsigned long long)(0xFFFFFFFFu - (unsigned)(lane + (bs << 6))));
#pragma unroll
    for (int off2 = 32; off2 > 0; off2 >>= 1) {
      unsigned long long o = __shfl_xor(packed, off2, 64);
      if (o > packed) packed = o;
    }
    unsigned jw = 0xFFFFFFFFu - (unsigned)(packed & 0xFFFFFFFFull);
    if ((int)(jw & 63u) == lane) removed |= 1ull << (jw >> 6);
    if (t == lane) myj = jw;
  }
  if (lane < 20) atomicOr(&M[(size_t)i * 80 + (myj >> 5)], 1u << (myj & 31u));
}

// ---------- 4. symmetrize mask, build padded CSR of W, row sums D, dsi ----------
__global__ void k_csr(const unsigned short* __restrict__ C0,
                      const unsigned short* __restrict__ C1,
                      const float* __restrict__ sq,
                      const unsigned* __restrict__ M, int* __restrict__ colG,
                      float* __restrict__ svalG, int* __restrict__ degG,
                      float* __restrict__ dsi) {
  int i = blockIdx.x, t = threadIdx.x;
  __shared__ unsigned Mrow[80];
  __shared__ int degs;
  __shared__ int cols[CAP];
  __shared__ float wvs[CAP];
  __shared__ float red[256];
  if (t < 80) Mrow[t] = M[(size_t)i * 80 + t];
  if (t == 0) degs = 0;
  __syncthreads();
  const unsigned short* r0c = C0 + (size_t)i * N;
  const unsigned short* r1c = C1 + (size_t)i * N;
  float sqi = sq[i];
  int iw = i >> 5; unsigned ib = 1u << (i & 31);
  float dsum = 0.f;
#pragma unroll
  for (int s = 0; s < 10; ++s) {
    int j = t + (s << 8);
    unsigned mij = (Mrow[j >> 5] >> (j & 31)) & 1u;
    unsigned mji = M[(size_t)j * 80 + iw] & ib;
    if (mij | (mji != 0u)) {
      float c = bf2f(r0c[j]) + bf2f(r1c[j]);
      float wv = expf((2.f * c - sqi - sq[j]) * (1.f / 16384.f));
      int sl = atomicAdd(&degs, 1);
      if (sl < CAP) { cols[sl] = j; wvs[sl] = wv; }
      dsum += wv;
    }
  }
  red[t] = dsum; __syncthreads();
  for (int o = 128; o > 0; o >>= 1) { if (t < o) red[t] += red[t + o]; __syncthreads(); }
  if (t == 0) {
    degG[i] = degs > CAP ? CAP : degs;
    dsi[i] = 1.f / sqrtf(red[0] + EPSF);
  }
  __syncthreads();
  int dgc = degs > CAP ? CAP : degs;
  for (int sl = t; sl < dgc; sl += 256) {
    colG[(size_t)i * CAP + sl] = cols[sl];
    svalG[(size_t)i * CAP + sl] = wvs[sl];
  }
}

// ---------- 5. merged: S edge scaling + Chebyshev init ----------
__global__ void k_scale_init(const int* __restrict__ colG, float* __restrict__ svalG,
                             const int* __restrict__ degG, const float* __restrict__ dsi,
                             const int* __restrict__ slab, float* __restrict__ x,
                             float* __restrict__ r, float* __restrict__ d0) {
  int i = blockIdx.x * 4 + (threadIdx.x >> 6);
  int lane = threadIdx.x & 63;
  float di = dsi[i];
  int dg = degG[i];
  for (int s = lane; s < dg; s += 64)
    svalG[(size_t)i * CAP + s] *= di * dsi[colG[(size_t)i * CAP + s]];
  int c0 = 2 * lane;
  float y0 = 0.f, y1 = 0.f;
  if (i < NSUP) {
    int lbl = slab[i];
    y0 = (lbl == c0) ? 1.f : 0.f;
    y1 = (lbl == c0 + 1) ? 1.f : 0.f;
  }
  size_t o = (size_t)i * NCLS + c0;
  x[o] = 0.f; x[o + 1] = 0.f;
  r[o] = y0;  r[o + 1] = y1;
  d0[o] = y0; d0[o + 1] = y1;
}

// ---------- 6. one Chebyshev iteration (A = I - alpha*S) ----------
// Block per row, 256 threads: g = t&31 (class group of 4), p = t>>5 (8 edge
// partitions). 8-deep unrolled main loop + 1-deep tail. 4 waves/row halves
// total wave count vs 512-thread blocks (dispatch-batch bound).
__global__ __launch_bounds__(256) void k_cheby(const int* __restrict__ colG,
                        const float* __restrict__ svalG,
                        const int* __restrict__ degG, const float* __restrict__ rho_tab,
                        const float* __restrict__ alpha, float* __restrict__ x,
                        float* __restrict__ r, const float* __restrict__ dcur,
                        float* __restrict__ dnxt, int it) {
  int i = blockIdx.x;
  int t = threadIdx.x;
  int g4 = (t & 31) << 2, p = t >> 5;
  __shared__ int lcol[CAP];
  __shared__ float lval[CAP];
  __shared__ float4 partial[256];
  int dg = degG[i];
  for (int s = t; s < dg; s += 256) {
    lcol[s] = colG[(size_t)i * CAP + s];
    lval[s] = svalG[(size_t)i * CAP + s];
  }
  __syncthreads();
  float4 acc = make_float4(0.f, 0.f, 0.f, 0.f);
  int s = p;
  for (; s + 56 < dg; s += 64) {         // 8 partitions x 8-deep unroll
    float4 a[8]; float v[8];
#pragma unroll
    for (int u = 0; u < 8; ++u) {
      int j = lcol[s + 8 * u];
      v[u] = lval[s + 8 * u];
      a[u] = *(const float4*)(dcur + (size_t)j * NCLS + g4);
    }
#pragma unroll
    for (int u = 0; u < 8; ++u) {
      acc.x = fmaf(v[u], a[u].x, acc.x);
      acc.y = fmaf(v[u], a[u].y, acc.y);
      acc.z = fmaf(v[u], a[u].z, acc.z);
      acc.w = fmaf(v[u], a[u].w, acc.w);
    }
  }
  for (; s < dg; s += 8) {               // tail
    int j = lcol[s];
    float v = lval[s];
    float4 a = *(const float4*)(dcur + (size_t)j * NCLS + g4);
    acc.x = fmaf(v, a.x, acc.x); acc.y = fmaf(v, a.y, acc.y);
    acc.z = fmaf(v, a.z, acc.z); acc.w = fmaf(v, a.w, acc.w);
  }
  partial[t] = acc;
  __syncthreads();
  for (int off = 128; off >= 32; off >>= 1) {
    if (t < off) {
      float4 o = partial[t + off];
      float4 m = partial[t];
      m.x += o.x; m.y += o.y; m.z += o.z; m.w += o.w;
      partial[t] = m;
    }
    __syncthreads();
  }
  if (t < 32) {                          // classes 4t..4t+3
    float4 ax = partial[t];
    float ahat = alpha[0];
    float rho = rho_tab[it], rhon = rho_tab[it + 1];
    float cc1 = rhon * rho, cc2 = 2.f * rhon / ahat;
    size_t o = (size_t)i * NCLS + 4 * t;
    float4 di = *(const float4*)(dcur + o);
    float4 xv = *(float4*)(x + o);
    float4 rv = *(float4*)(r + o);
    float4 q;
    q.x = di.x - ahat * ax.x; q.y = di.y - ahat * ax.y;
    q.z = di.z - ahat * ax.z; q.w = di.w - ahat * ax.w;
    xv.x += di.x; xv.y += di.y; xv.z += di.z; xv.w += di.w;
    rv.x -= q.x; rv.y -= q.y; rv.z -= q.z; rv.w -= q.w;
    float4 dn;
    dn.x = cc1 * di.x + cc2 * rv.x; dn.y = cc1 * di.y + cc2 * rv.y;
    dn.z = cc1 * di.z + cc2 * rv.z; dn.w = cc1 * di.w + cc2 * rv.w;
    *(float4*)(x + o) = xv;
    *(float4*)(r + o) = rv;
    *(float4*)(dnxt + o) = dn;
  }
}

// ---------- 7. loss + acc ----------
__global__ void k_loss(const float* __restrict__ F, const int* __restrict__ slab,
                       const int* __restrict__ qlab, float* __restrict__ lossSum,
                       int* __restrict__ accCnt) {
  int i = blockIdx.x * 4 + (threadIdx.x >> 6);
  int lane = threadIdx.x & 63;
  int c0 = 2 * lane;
  float2 f = *(const float2*)(F + (size_t)i * NCLS + c0);
  float mx = fmaxf(f.x, f.y);
  for (int o2 = 32; o2 > 0; o2 >>= 1) mx = fmaxf(mx, __shfl_xor(mx, o2, 64));
  float se = expf(f.x - mx) + expf(f.y - mx);
  for (int o2 = 32; o2 > 0; o2 >>= 1) se += __shfl_xor(se, o2, 64);
  float lse = mx + logf(se);
  int gt = (i < NSUP) ? slab[i] : qlab[i - NSUP];
  float fg = ((c0 == gt) ? f.x : 0.f) + ((c0 + 1 == gt) ? f.y : 0.f);
  for (int o2 = 32; o2 > 0; o2 >>= 1) fg += __shfl_xor(fg, o2, 64);
  if (lane == 0) atomicAdd(lossSum, fg - lse);
  if (i >= NSUP) {
    float bvv; int bc;
    if (f.y > f.x) { bvv = f.y; bc = c0 + 1; } else { bvv = f.x; bc = c0; }
    unsigned long long packed =
        (((unsigned long long)sortkey(bvv)) << 32) | (unsigned long long)(unsigned)(127 - bc);
    for (int o2 = 32; o2 > 0; o2 >>= 1) {
      unsigned long long o = __shfl_xor(packed, o2, 64);
      if (o > packed) packed = o;
    }
    int cw = 127 - (int)(packed & 0xFFFFFFFFull);
    if (lane == 0 && cw == qlab[i - NSUP]) atomicAdd(accCnt, 1);
  }
}

// ---------- 8. finalize ----------
__global__ void k_final(const float* __restrict__ lossSum, const int* __restrict__ accCnt,
                        float* __restrict__ out) {
  out[0] = -lossSum[0] / (float)N;
  out[1] = (float)accCnt[0] / (float)NQ;
}

// ---------- launch ----------
extern "C" void kernel_launch(void* const* d_in, const int* in_sizes, int n_in,
                              void* d_out, int out_size, void* d_ws, size_t ws_size,
                              hipStream_t stream) {
  const float* feats = (const float*)d_in[0];
  const float* alpha = (const float*)d_in[1];
  const int* slab = (const int*)d_in[2];
  const int* qlab = (const int*)d_in[3];
  float* out = (float*)d_out;
  char* ws = (char*)d_ws;

  // ws layout (bytes). C0/C1 (bf16, 13,107,200 each) reused for x/r/d0/d1 after CSR.
  unsigned short* C0 = (unsigned short*)(ws + 0);
  unsigned short* C1 = (unsigned short*)(ws + 13107200);
  float* x      = (float*)(ws + 0);
  float* r      = (float*)(ws + 1310720);
  float* d0     = (float*)(ws + 2621440);
  float* d1     = (float*)(ws + 3932160);
  unsigned* M   = (unsigned*)(ws + 26214400);          // 819,200 B bitmask
  float* ctrl   = (float*)(ws + 27033600);             // 1,024 B: lossSum, accCnt, rho_tab
  float* lossSum = ctrl;
  int* accCnt   = (int*)(ctrl + 1);
  float* rho_tab = ctrl + 4;                           // 128 floats
  float* sq     = (float*)(ws + 27034624);
  float* dsi    = (float*)(ws + 27044864);
  int* degG     = (int*)(ws + 27055104);
  unsigned short* fb = (unsigned short*)(ws + 27065344);          // 41,943,040 B
  int* colG     = (int*)(ws + 27065344);               // overlays fb after GEMM
  float* svalG  = (float*)(ws + 27065344 + 10485760);  // overlays fb after GEMM
  // total ws required: 69,008,384 bytes

  hipMemsetAsync(ws + 26214400, 0, 820224, stream);    // M + ctrl
  k_prep<<<N, 256, 0, stream>>>(feats, fb, sq, alpha, rho_tab);
  k_gemm<<<420, 256, 0, stream>>>(fb, C0, C1);         // lower-tri tiles, split-K x2
  k_topk<<<N / 4, 256, 0, stream>>>(C0, C1, sq, M);
  k_csr<<<N, 256, 0, stream>>>(C0, C1, sq, M, colG, svalG, degG, dsi);
  k_scale_init<<<N / 4, 256, 0, stream>>>(colG, svalG, degG, dsi, slab, x, r, d0);
  for (int it = 0; it < TITER; ++it) {
    const float* dc = (it & 1) ? d1 : d0;
    float* dn = (it & 1) ? d0 : d1;
    k_cheby<<<N, 256, 0, stream>>>(colG, svalG, degG, rho_tab, alpha, x, r, dc, dn, it);
  }
  k_loss<<<N / 4, 256, 0, stream>>>(x, slab, qlab, lossSum, accCnt);
  k_final<<<1, 1, 0, stream>>>(lossSum, accCnt, out);
}